// Round 1
// baseline (3402.350 us; speedup 1.0000x reference)
//
#include <hip/hip_runtime.h>
#include <math.h>

#define D_   1024
#define H_   16
#define DK_  64
#define L_   512
#define NB_  16
#define FF_  4096
#define M_   (NB_*L_)   // 8192 tokens
#define EPS_ 1e-5f

__device__ __forceinline__ float gelu_exact(float x){
    return 0.5f * x * (1.f + erff(x * 0.7071067811865476f));
}

// ---------------------------------------------------------------------------
// Tiled fp32 GEMM: C = A[M,K] @ B[K,N] + bias, with fused epilogue.
// EPI 0: scatter to [n,h,l,dk] (QKV projections)
// EPI 1: + residual res[M,N], store row-major
// EPI 2: exact GELU, store row-major
// BM=BN=128, BK=16, 256 threads, 8x8 micro-tile.
// ---------------------------------------------------------------------------
template<int EPI>
__global__ __launch_bounds__(256)
void gemm_k(const float* __restrict__ A, const float* __restrict__ B,
            const float* __restrict__ bias, const float* __restrict__ res,
            float* __restrict__ C, int M, int N, int K)
{
    __shared__ float As[16][132];   // [k][m], padded (132*4B = 33*16B aligned)
    __shared__ float Bs[16][132];   // [k][n], padded
    const int tid = threadIdx.x;
    const int tx = tid & 15, ty = tid >> 4;
    const int bm = blockIdx.y * 128, bn = blockIdx.x * 128;

    float acc[8][8];
#pragma unroll
    for (int i = 0; i < 8; ++i)
#pragma unroll
        for (int j = 0; j < 8; ++j) acc[i][j] = 0.f;

    for (int k0 = 0; k0 < K; k0 += 16) {
        float4 av[2], bv[2];
#pragma unroll
        for (int it = 0; it < 2; ++it) {
            int f = tid + it * 256;
            int ar = f >> 2, ak = (f & 3) * 4;        // A tile: 128 rows x 16 k
            av[it] = *(const float4*)&A[(size_t)(bm + ar) * K + k0 + ak];
            int br = f >> 5, bc = (f & 31) * 4;       // B tile: 16 k x 128 cols
            bv[it] = *(const float4*)&B[(size_t)(k0 + br) * N + bn + bc];
        }
        __syncthreads();   // previous iter done reading LDS
#pragma unroll
        for (int it = 0; it < 2; ++it) {
            int f = tid + it * 256;
            int ar = f >> 2, ak = (f & 3) * 4;
            As[ak + 0][ar] = av[it].x; As[ak + 1][ar] = av[it].y;
            As[ak + 2][ar] = av[it].z; As[ak + 3][ar] = av[it].w;
            int br = f >> 5, bc = (f & 31) * 4;
            *(float4*)&Bs[br][bc] = bv[it];
        }
        __syncthreads();
#pragma unroll
        for (int kk = 0; kk < 16; ++kk) {
            float4 a0 = *(const float4*)&As[kk][ty * 4];
            float4 a1 = *(const float4*)&As[kk][ty * 4 + 64];
            float4 b0 = *(const float4*)&Bs[kk][tx * 4];
            float4 b1 = *(const float4*)&Bs[kk][tx * 4 + 64];
            float aa[8] = {a0.x, a0.y, a0.z, a0.w, a1.x, a1.y, a1.z, a1.w};
            float bb[8] = {b0.x, b0.y, b0.z, b0.w, b1.x, b1.y, b1.z, b1.w};
#pragma unroll
            for (int i = 0; i < 8; ++i)
#pragma unroll
                for (int j = 0; j < 8; ++j)
                    acc[i][j] = fmaf(aa[i], bb[j], acc[i][j]);
        }
    }

#pragma unroll
    for (int i = 0; i < 8; ++i) {
        int row = bm + ty * 4 + (i & 3) + (i >> 2) * 64;
#pragma unroll
        for (int jh = 0; jh < 2; ++jh) {
            int col = bn + tx * 4 + jh * 64;
            float4 v;
            v.x = acc[i][jh * 4 + 0] + bias[col + 0];
            v.y = acc[i][jh * 4 + 1] + bias[col + 1];
            v.z = acc[i][jh * 4 + 2] + bias[col + 2];
            v.w = acc[i][jh * 4 + 3] + bias[col + 3];
            if (EPI == 0) {
                int n = row >> 9, l = row & (L_ - 1);
                int hh = col >> 6, d = col & (DK_ - 1);
                *(float4*)&C[(((size_t)n * H_ + hh) * L_ + l) * DK_ + d] = v;
            } else if (EPI == 1) {
                const float4 r = *(const float4*)&res[(size_t)row * N + col];
                v.x += r.x; v.y += r.y; v.z += r.z; v.w += r.w;
                *(float4*)&C[(size_t)row * N + col] = v;
            } else {
                v.x = gelu_exact(v.x); v.y = gelu_exact(v.y);
                v.z = gelu_exact(v.z); v.w = gelu_exact(v.w);
                *(float4*)&C[(size_t)row * N + col] = v;
            }
        }
    }
}

// ---------------------------------------------------------------------------
// Attention: one block = one (n,h) pair x 16 q-rows. Two-pass (scores in LDS).
// S[16][512] fp32 in LDS; K/V tiles of 64 rows staged in LDS.
// q/k/v layout: [n,h,l,dk]. ctx written to [n,l,d].
// ---------------------------------------------------------------------------
__global__ __launch_bounds__(256)
void attn_k(const float* __restrict__ qb, const float* __restrict__ kb,
            const float* __restrict__ vb, const unsigned char* __restrict__ mask,
            float* __restrict__ ctx)
{
    __shared__ float S[16][524];     // pad 512->524: 2-way banks, 16B-aligned rows
    __shared__ float Qs[16][76];
    __shared__ float KVs[64][76];
    __shared__ float red[16][17];
    __shared__ float rowmax_[16];
    __shared__ float rowinv_[16];

    const int tid = threadIdx.x;
    const int qt = blockIdx.x;            // 0..31
    const int nh = blockIdx.y;            // 0..255
    const int n = nh >> 4, hh = nh & 15;
    const int q0 = qt * 16;
    const float* qbase = qb + ((size_t)nh * L_ + q0) * DK_;
    const float* kbase = kb + (size_t)nh * L_ * DK_;
    const float* vbase = vb + (size_t)nh * L_ * DK_;

    {   // Q tile: 16x64 = 1024 contiguous floats
        float4 t = *(const float4*)&qbase[tid * 4];
        *(float4*)&Qs[tid >> 4][(tid & 15) * 4] = t;
    }

    const int qrow = tid & 15;
    const int kk4 = (tid >> 4) * 4;       // this thread's 4 k-columns in tile

    // ---- pass 1: S = Q K^T / sqrt(dk), masked ----
    for (int kt = 0; kt < 8; ++kt) {
        __syncthreads();
#pragma unroll
        for (int it = 0; it < 4; ++it) {
            int f = tid + it * 256;
            int r = f >> 4, c = (f & 15) * 4;
            *(float4*)&KVs[r][c] = *(const float4*)&kbase[(size_t)(kt * 64 + r) * DK_ + c];
        }
        __syncthreads();
        float sacc[4] = {0.f, 0.f, 0.f, 0.f};
#pragma unroll
        for (int d = 0; d < 64; d += 4) {
            float4 qv = *(const float4*)&Qs[qrow][d];
#pragma unroll
            for (int jj = 0; jj < 4; ++jj) {
                float4 kv = *(const float4*)&KVs[kk4 + jj][d];
                sacc[jj] += qv.x * kv.x + qv.y * kv.y + qv.z * kv.z + qv.w * kv.w;
            }
        }
        const int kcb = kt * 64 + kk4;
        const unsigned int mw =
            *(const unsigned int*)&mask[((size_t)n * L_ + q0 + qrow) * L_ + kcb];
#pragma unroll
        for (int jj = 0; jj < 4; ++jj) {
            float sv = sacc[jj] * 0.125f;       // 1/sqrt(64)
            if ((mw >> (jj * 8)) & 0xffu) sv = -INFINITY;
            S[qrow][kcb + jj] = sv;
        }
    }
    __syncthreads();

    // ---- softmax over S rows (16 segs x 32 per row) ----
    const int seg = tid >> 4;
    float m = -INFINITY;
#pragma unroll 8
    for (int i = 0; i < 32; ++i) m = fmaxf(m, S[qrow][seg * 32 + i]);
    red[qrow][seg] = m;
    __syncthreads();
    if (tid < 16) {
        float mm = -INFINITY;
        for (int s2 = 0; s2 < 16; ++s2) mm = fmaxf(mm, red[tid][s2]);
        rowmax_[tid] = mm;
    }
    __syncthreads();
    const float rm = rowmax_[qrow];
    float psum = 0.f;
    if (rm == -INFINITY) {                 // fully-masked row -> attn = 0
        for (int i = 0; i < 32; ++i) S[qrow][seg * 32 + i] = 0.f;
    } else {
#pragma unroll 8
        for (int i = 0; i < 32; ++i) {
            float pv = __expf(S[qrow][seg * 32 + i] - rm);
            S[qrow][seg * 32 + i] = pv;
            psum += pv;
        }
    }
    red[qrow][seg] = psum;
    __syncthreads();
    if (tid < 16) {
        float sum = 0.f;
        for (int s2 = 0; s2 < 16; ++s2) sum += red[tid][s2];
        rowinv_[tid] = sum > 0.f ? 1.f / sum : 0.f;
    }

    // ---- pass 2: ctx = P V ----
    const int dd = tid >> 4;               // 16 d-groups of 4
    float oa[4] = {0.f, 0.f, 0.f, 0.f};
    for (int kt = 0; kt < 8; ++kt) {
        __syncthreads();                   // also publishes rowinv_ on kt=0
#pragma unroll
        for (int it = 0; it < 4; ++it) {
            int f = tid + it * 256;
            int r = f >> 4, c = (f & 15) * 4;
            *(float4*)&KVs[r][c] = *(const float4*)&vbase[(size_t)(kt * 64 + r) * DK_ + c];
        }
        __syncthreads();
#pragma unroll 16
        for (int k = 0; k < 64; ++k) {
            float pv = S[qrow][kt * 64 + k];
            float4 vv = *(const float4*)&KVs[k][dd * 4];
            oa[0] = fmaf(pv, vv.x, oa[0]);
            oa[1] = fmaf(pv, vv.y, oa[1]);
            oa[2] = fmaf(pv, vv.z, oa[2]);
            oa[3] = fmaf(pv, vv.w, oa[3]);
        }
    }
    const float sc = rowinv_[qrow];
    float4 o;
    o.x = oa[0] * sc; o.y = oa[1] * sc; o.z = oa[2] * sc; o.w = oa[3] * sc;
    *(float4*)&ctx[((size_t)n * L_ + q0 + qrow) * D_ + hh * DK_ + dd * 4] = o;
}

// ---------------------------------------------------------------------------
// Row LayerNorm: one block per row of 1024, 256 threads x float4.
// ---------------------------------------------------------------------------
__global__ __launch_bounds__(256)
void ln_k(const float* __restrict__ in, const float* __restrict__ g,
          const float* __restrict__ b, float* __restrict__ out)
{
    const int row = blockIdx.x, tid = threadIdx.x;
    const float* p = in + (size_t)row * D_;
    float4 v = *(const float4*)&p[tid * 4];
    float s = v.x + v.y + v.z + v.w;
#pragma unroll
    for (int off = 32; off > 0; off >>= 1) s += __shfl_down(s, off);
    __shared__ float wsum[4];
    const int wid = tid >> 6, lane = tid & 63;
    if (lane == 0) wsum[wid] = s;
    __syncthreads();
    const float mu = (wsum[0] + wsum[1] + wsum[2] + wsum[3]) * (1.f / D_);
    const float dx = v.x - mu, dy = v.y - mu, dz = v.z - mu, dw = v.w - mu;
    float q = dx * dx + dy * dy + dz * dz + dw * dw;
#pragma unroll
    for (int off = 32; off > 0; off >>= 1) q += __shfl_down(q, off);
    __syncthreads();                      // wsum reuse
    if (lane == 0) wsum[wid] = q;
    __syncthreads();
    const float var = (wsum[0] + wsum[1] + wsum[2] + wsum[3]) * (1.f / D_);
    const float rs = rsqrtf(var + EPS_);
    const float4 gg = *(const float4*)&g[tid * 4];
    const float4 bb = *(const float4*)&b[tid * 4];
    float4 o;
    o.x = dx * rs * gg.x + bb.x;
    o.y = dy * rs * gg.y + bb.y;
    o.z = dz * rs * gg.z + bb.z;
    o.w = dw * rs * gg.w + bb.w;
    *(float4*)&out[(size_t)row * D_ + tid * 4] = o;
}

// ---------------------------------------------------------------------------
extern "C" void kernel_launch(void* const* d_in, const int* in_sizes, int n_in,
                              void* d_out, int out_size, void* d_ws, size_t ws_size,
                              hipStream_t stream)
{
    const float* x  = (const float*)d_in[0];
    const unsigned char* mask = (const unsigned char*)d_in[1];
    const float* WQ = (const float*)d_in[2];
    const float* bQ = (const float*)d_in[3];
    const float* WK = (const float*)d_in[4];
    const float* bK = (const float*)d_in[5];
    const float* WV = (const float*)d_in[6];
    const float* bV = (const float*)d_in[7];
    const float* WO = (const float*)d_in[8];
    const float* bO = (const float*)d_in[9];
    const float* g0 = (const float*)d_in[10];
    const float* b0 = (const float*)d_in[11];
    const float* W1 = (const float*)d_in[12];
    const float* b1 = (const float*)d_in[13];
    const float* W2 = (const float*)d_in[14];
    const float* b2 = (const float*)d_in[15];
    const float* g1 = (const float*)d_in[16];
    const float* b1n = (const float*)d_in[17];
    float* out = (float*)d_out;

    const size_t MD = (size_t)M_ * D_;
    float* ws   = (float*)d_ws;
    float* qbuf = ws;            // [n,h,l,dk]
    float* kbuf = ws + MD;       // [n,h,l,dk]; later reused as ff2 output
    float* vbuf = ws + 2 * MD;   // [n,h,l,dk]
    float* cbuf = ws + 3 * MD;   // ctx [n,l,d]
    float* fbuf = ws + 4 * MD;   // ff1 activations [M, FF] = 4*MD floats
    float* hbuf = out;           // h (post-LN0) parked in d_out until final LN

    dim3 blk(256);
    dim3 gD(D_ / 128, M_ / 128);    // (8, 64)
    dim3 gF(FF_ / 128, M_ / 128);   // (32, 64)

    gemm_k<0><<<gD, blk, 0, stream>>>(x, WQ, bQ, nullptr, qbuf, M_, D_, D_);
    gemm_k<0><<<gD, blk, 0, stream>>>(x, WK, bK, nullptr, kbuf, M_, D_, D_);
    gemm_k<0><<<gD, blk, 0, stream>>>(x, WV, bV, nullptr, vbuf, M_, D_, D_);
    attn_k<<<dim3(L_ / 16, NB_ * H_), blk, 0, stream>>>(qbuf, kbuf, vbuf, mask, cbuf);
    gemm_k<1><<<gD, blk, 0, stream>>>(cbuf, WO, bO, x, qbuf, M_, D_, D_);   // mha + x
    ln_k<<<dim3(M_), blk, 0, stream>>>(qbuf, g0, b0, hbuf);                  // h
    gemm_k<2><<<gF, blk, 0, stream>>>(hbuf, W1, b1, nullptr, fbuf, M_, FF_, D_); // gelu(h W1 + b1)
    gemm_k<1><<<gD, blk, 0, stream>>>(fbuf, W2, b2, hbuf, kbuf, M_, D_, FF_);    // ff + h
    ln_k<<<dim3(M_), blk, 0, stream>>>(kbuf, g1, b1n, out);
}

// Round 4
// 1468.082 us; speedup vs baseline: 2.3175x; 2.3175x over previous
//
#include <hip/hip_runtime.h>
#include <math.h>

#define D_   1024
#define H_   16
#define DK_  64
#define L_   512
#define NB_  16
#define FF_  4096
#define M_   (NB_*L_)   // 8192 tokens
#define EPS_ 1e-5f

typedef __attribute__((ext_vector_type(8))) __bf16 bf16x8;
typedef __attribute__((ext_vector_type(4))) float f32x4;
typedef __attribute__((ext_vector_type(4))) unsigned short us4;
typedef __attribute__((ext_vector_type(8))) unsigned short us8;

__device__ __forceinline__ float gelu_exact(float x){
    return 0.5f * x * (1.f + erff(x * 0.7071067811865476f));
}

// split fp32 -> bf16 hi (truncate) + bf16 lo (truncated remainder), packed:
// low 16 bits = hi part, high 16 bits = lo part. ~2^-16 rel err on product.
__device__ __forceinline__ unsigned split1(float a){
    unsigned ab = __builtin_bit_cast(unsigned, a);
    unsigned short h = (unsigned short)(ab >> 16);
    float hif = __builtin_bit_cast(float, ab & 0xffff0000u);
    float rem = a - hif;
    unsigned short lo = (unsigned short)(__builtin_bit_cast(unsigned, rem) >> 16);
    return (unsigned)h | ((unsigned)lo << 16);
}

// ---------------------------------------------------------------------------
// Split-bf16 MFMA GEMM: C = A[M,K] @ B[K,N] + bias, fused epilogue.
// EPI 0: scatter to [n,h,l,dk]   EPI 1: + res[M,N]   EPI 2: exact GELU
// BM=BN=128, BK=32, 256 threads (4 waves), each wave 64x64 via 4x4 frags of
// 16x16x32. LDS: A/B hi+lo tiles in fragment-lane-order subtiled layout:
// subtile s (16 rows/cols x 32 k) stored as lane l's 8 bf16 at s*1024+l*16 B,
// element (rc, k): l = (k>>3)*16 + (rc&15), j = k&7.  -> conflict-free b128
// reads (1KiB contiguous per wave) and conflict-free staged writes.
// ---------------------------------------------------------------------------
template<int EPI>
__global__ __launch_bounds__(256, 2)
void gemm_mfma(const float* __restrict__ A, const float* __restrict__ B,
               const float* __restrict__ bias, const float* __restrict__ res,
               float* __restrict__ C, int M, int N, int K)
{
    __shared__ __align__(16) unsigned short Ah[4096];
    __shared__ __align__(16) unsigned short Al[4096];
    __shared__ __align__(16) unsigned short Bh[4096];
    __shared__ __align__(16) unsigned short Bl[4096];

    const int t = threadIdx.x;
    const int bm = blockIdx.y * 128, bn = blockIdx.x * 128;
    const int l = t & 63, w = t >> 6, wr = w >> 1, wc = w & 1;

    // ---- staging address precompute ----
    // A tile: 128 rows x 32 k fp32, flat float4 f = t + 256*i
    size_t gA[4]; int lA[4];
#pragma unroll
    for (int i = 0; i < 4; ++i) {
        int f = t + 256 * i;
        int r = f >> 3, k0 = (f & 7) * 4;
        gA[i] = (size_t)(bm + r) * K + k0;
        lA[i] = ((r >> 4) << 9) + (((k0 >> 3) << 4) + (r & 15)) * 8 + (k0 & 7);
    }
    // B tile: 32 k x 128 cols; thread owns col c, k-range kq*16..+15
    const int c = t & 127, kq = t >> 7;
    const size_t gB = (size_t)(kq * 16) * N + bn + c;
    const int lB = ((c >> 4) << 9) + (kq * 2 * 16 + (c & 15)) * 8;

    f32x4 acc[4][4] = {};

    float4 aA[4];
    float  bB[16];
#pragma unroll
    for (int i = 0; i < 4; ++i) aA[i] = *(const float4*)&A[gA[i]];
#pragma unroll
    for (int i = 0; i < 16; ++i) bB[i] = B[gB + (size_t)i * N];

    const int nk = K >> 5;
    for (int ks = 0; ks < nk; ++ks) {
        __syncthreads();                       // prev-iter LDS reads done
        // ---- convert + LDS write ----
#pragma unroll
        for (int i = 0; i < 4; ++i) {
            us4 h, lo;
            unsigned p0 = split1(aA[i].x), p1 = split1(aA[i].y);
            unsigned p2 = split1(aA[i].z), p3 = split1(aA[i].w);
            h.x = (unsigned short)p0; lo.x = (unsigned short)(p0 >> 16);
            h.y = (unsigned short)p1; lo.y = (unsigned short)(p1 >> 16);
            h.z = (unsigned short)p2; lo.z = (unsigned short)(p2 >> 16);
            h.w = (unsigned short)p3; lo.w = (unsigned short)(p3 >> 16);
            *(us4*)&Ah[lA[i]] = h;
            *(us4*)&Al[lA[i]] = lo;
        }
        {
            us8 h0, l0, h1, l1;
#pragma unroll
            for (int i = 0; i < 8; ++i) {
                unsigned p = split1(bB[i]);
                h0[i] = (unsigned short)p; l0[i] = (unsigned short)(p >> 16);
            }
#pragma unroll
            for (int i = 0; i < 8; ++i) {
                unsigned p = split1(bB[8 + i]);
                h1[i] = (unsigned short)p; l1[i] = (unsigned short)(p >> 16);
            }
            *(us8*)&Bh[lB] = h0;       *(us8*)&Bl[lB] = l0;
            *(us8*)&Bh[lB + 128] = h1; *(us8*)&Bl[lB + 128] = l1;
        }
        __syncthreads();                       // tile ready
        // ---- prefetch next K-step while computing ----
        if (ks + 1 < nk) {
            const int ko = (ks + 1) * 32;
#pragma unroll
            for (int i = 0; i < 4; ++i) aA[i] = *(const float4*)&A[gA[i] + ko];
#pragma unroll
            for (int i = 0; i < 16; ++i) bB[i] = B[gB + (size_t)(ko + i) * N];
        }
        // ---- fragments + MFMA ----
        bf16x8 ah[4], al4[4];
#pragma unroll
        for (int m = 0; m < 4; ++m) {
            const int idx = (wr * 4 + m) * 512 + l * 8;
            ah[m]  = *(const bf16x8*)&Ah[idx];
            al4[m] = *(const bf16x8*)&Al[idx];
        }
#pragma unroll
        for (int n = 0; n < 4; ++n) {
            const int idx = (wc * 4 + n) * 512 + l * 8;
            bf16x8 bh = *(const bf16x8*)&Bh[idx];
            bf16x8 bl = *(const bf16x8*)&Bl[idx];
#pragma unroll
            for (int m = 0; m < 4; ++m) {
                acc[m][n] = __builtin_amdgcn_mfma_f32_16x16x32_bf16(ah[m],  bh, acc[m][n], 0, 0, 0);
                acc[m][n] = __builtin_amdgcn_mfma_f32_16x16x32_bf16(ah[m],  bl, acc[m][n], 0, 0, 0);
                acc[m][n] = __builtin_amdgcn_mfma_f32_16x16x32_bf16(al4[m], bh, acc[m][n], 0, 0, 0);
            }
        }
    }

    // ---- epilogue: C/D layout col = lane&15, row = (lane>>4)*4 + j ----
#pragma unroll
    for (int n = 0; n < 4; ++n) {
        const int col = bn + wc * 64 + n * 16 + (l & 15);
        const float bv = bias[col];
#pragma unroll
        for (int m = 0; m < 4; ++m) {
            const int rowb = bm + wr * 64 + m * 16 + ((l >> 4) << 2);
#pragma unroll
            for (int j = 0; j < 4; ++j) {
                const int row = rowb + j;
                float v = acc[m][n][j] + bv;
                if (EPI == 0) {
                    const int nb = row >> 9, ll = row & (L_ - 1);
                    const int hh = col >> 6, d = col & (DK_ - 1);
                    C[(((size_t)nb * H_ + hh) * L_ + ll) * DK_ + d] = v;
                } else if (EPI == 1) {
                    v += res[(size_t)row * N + col];
                    C[(size_t)row * N + col] = v;
                } else {
                    C[(size_t)row * N + col] = gelu_exact(v);
                }
            }
        }
    }
}

// ---------------------------------------------------------------------------
// Attention: one block = one (n,h) pair x 16 q-rows. Two-pass (scores in LDS).
// ---------------------------------------------------------------------------
__global__ __launch_bounds__(256)
void attn_k(const float* __restrict__ qb, const float* __restrict__ kb,
            const float* __restrict__ vb, const unsigned char* __restrict__ mask,
            float* __restrict__ ctx)
{
    __shared__ float S[16][524];
    __shared__ float Qs[16][76];
    __shared__ float KVs[64][76];
    __shared__ float red[16][17];
    __shared__ float rowmax_[16];
    __shared__ float rowinv_[16];

    const int tid = threadIdx.x;
    const int qt = blockIdx.x;
    const int nh = blockIdx.y;
    const int n = nh >> 4, hh = nh & 15;
    const int q0 = qt * 16;
    const float* qbase = qb + ((size_t)nh * L_ + q0) * DK_;
    const float* kbase = kb + (size_t)nh * L_ * DK_;
    const float* vbase = vb + (size_t)nh * L_ * DK_;

    {
        float4 tq = *(const float4*)&qbase[tid * 4];
        *(float4*)&Qs[tid >> 4][(tid & 15) * 4] = tq;
    }

    const int qrow = tid & 15;
    const int kk4 = (tid >> 4) * 4;

    for (int kt = 0; kt < 8; ++kt) {
        __syncthreads();
#pragma unroll
        for (int it = 0; it < 4; ++it) {
            int f = tid + it * 256;
            int r = f >> 4, cc = (f & 15) * 4;
            *(float4*)&KVs[r][cc] = *(const float4*)&kbase[(size_t)(kt * 64 + r) * DK_ + cc];
        }
        __syncthreads();
        float sacc[4] = {0.f, 0.f, 0.f, 0.f};
#pragma unroll
        for (int d = 0; d < 64; d += 4) {
            float4 qv = *(const float4*)&Qs[qrow][d];
#pragma unroll
            for (int jj = 0; jj < 4; ++jj) {
                float4 kv = *(const float4*)&KVs[kk4 + jj][d];
                sacc[jj] += qv.x * kv.x + qv.y * kv.y + qv.z * kv.z + qv.w * kv.w;
            }
        }
        const int kcb = kt * 64 + kk4;
        const unsigned int mw =
            *(const unsigned int*)&mask[((size_t)n * L_ + q0 + qrow) * L_ + kcb];
#pragma unroll
        for (int jj = 0; jj < 4; ++jj) {
            float sv = sacc[jj] * 0.125f;
            if ((mw >> (jj * 8)) & 0xffu) sv = -INFINITY;
            S[qrow][kcb + jj] = sv;
        }
    }
    __syncthreads();

    const int seg = tid >> 4;
    float m = -INFINITY;
#pragma unroll 8
    for (int i = 0; i < 32; ++i) m = fmaxf(m, S[qrow][seg * 32 + i]);
    red[qrow][seg] = m;
    __syncthreads();
    if (tid < 16) {
        float mm = -INFINITY;
        for (int s2 = 0; s2 < 16; ++s2) mm = fmaxf(mm, red[tid][s2]);
        rowmax_[tid] = mm;
    }
    __syncthreads();
    const float rm = rowmax_[qrow];
    float psum = 0.f;
    if (rm == -INFINITY) {
        for (int i = 0; i < 32; ++i) S[qrow][seg * 32 + i] = 0.f;
    } else {
#pragma unroll 8
        for (int i = 0; i < 32; ++i) {
            float pv = __expf(S[qrow][seg * 32 + i] - rm);
            S[qrow][seg * 32 + i] = pv;
            psum += pv;
        }
    }
    red[qrow][seg] = psum;
    __syncthreads();
    if (tid < 16) {
        float sum = 0.f;
        for (int s2 = 0; s2 < 16; ++s2) sum += red[tid][s2];
        rowinv_[tid] = sum > 0.f ? 1.f / sum : 0.f;
    }

    const int dd = tid >> 4;
    float oa[4] = {0.f, 0.f, 0.f, 0.f};
    for (int kt = 0; kt < 8; ++kt) {
        __syncthreads();
#pragma unroll
        for (int it = 0; it < 4; ++it) {
            int f = tid + it * 256;
            int r = f >> 4, cc = (f & 15) * 4;
            *(float4*)&KVs[r][cc] = *(const float4*)&vbase[(size_t)(kt * 64 + r) * DK_ + cc];
        }
        __syncthreads();
#pragma unroll 16
        for (int k = 0; k < 64; ++k) {
            float pv = S[qrow][kt * 64 + k];
            float4 vv = *(const float4*)&KVs[k][dd * 4];
            oa[0] = fmaf(pv, vv.x, oa[0]);
            oa[1] = fmaf(pv, vv.y, oa[1]);
            oa[2] = fmaf(pv, vv.z, oa[2]);
            oa[3] = fmaf(pv, vv.w, oa[3]);
        }
    }
    const float sc = rowinv_[qrow];
    float4 o;
    o.x = oa[0] * sc; o.y = oa[1] * sc; o.z = oa[2] * sc; o.w = oa[3] * sc;
    *(float4*)&ctx[((size_t)n * L_ + q0 + qrow) * D_ + hh * DK_ + dd * 4] = o;
}

// ---------------------------------------------------------------------------
// Row LayerNorm
// ---------------------------------------------------------------------------
__global__ __launch_bounds__(256)
void ln_k(const float* __restrict__ in, const float* __restrict__ g,
          const float* __restrict__ b, float* __restrict__ out)
{
    const int row = blockIdx.x, tid = threadIdx.x;
    const float* p = in + (size_t)row * D_;
    float4 v = *(const float4*)&p[tid * 4];
    float s = v.x + v.y + v.z + v.w;
#pragma unroll
    for (int off = 32; off > 0; off >>= 1) s += __shfl_down(s, off);
    __shared__ float wsum[4];
    const int wid = tid >> 6, lane = tid & 63;
    if (lane == 0) wsum[wid] = s;
    __syncthreads();
    const float mu = (wsum[0] + wsum[1] + wsum[2] + wsum[3]) * (1.f / D_);
    const float dx = v.x - mu, dy = v.y - mu, dz = v.z - mu, dw = v.w - mu;
    float q = dx * dx + dy * dy + dz * dz + dw * dw;
#pragma unroll
    for (int off = 32; off > 0; off >>= 1) q += __shfl_down(q, off);
    __syncthreads();
    if (lane == 0) wsum[wid] = q;
    __syncthreads();
    const float var = (wsum[0] + wsum[1] + wsum[2] + wsum[3]) * (1.f / D_);
    const float rs = rsqrtf(var + EPS_);
    const float4 gg = *(const float4*)&g[tid * 4];
    const float4 bb = *(const float4*)&b[tid * 4];
    float4 o;
    o.x = dx * rs * gg.x + bb.x;
    o.y = dy * rs * gg.y + bb.y;
    o.z = dz * rs * gg.z + bb.z;
    o.w = dw * rs * gg.w + bb.w;
    *(float4*)&out[(size_t)row * D_ + tid * 4] = o;
}

// ---------------------------------------------------------------------------
extern "C" void kernel_launch(void* const* d_in, const int* in_sizes, int n_in,
                              void* d_out, int out_size, void* d_ws, size_t ws_size,
                              hipStream_t stream)
{
    const float* x  = (const float*)d_in[0];
    const unsigned char* mask = (const unsigned char*)d_in[1];
    const float* WQ = (const float*)d_in[2];
    const float* bQ = (const float*)d_in[3];
    const float* WK = (const float*)d_in[4];
    const float* bK = (const float*)d_in[5];
    const float* WV = (const float*)d_in[6];
    const float* bV = (const float*)d_in[7];
    const float* WO = (const float*)d_in[8];
    const float* bO = (const float*)d_in[9];
    const float* g0 = (const float*)d_in[10];
    const float* b0 = (const float*)d_in[11];
    const float* W1 = (const float*)d_in[12];
    const float* b1 = (const float*)d_in[13];
    const float* W2 = (const float*)d_in[14];
    const float* b2 = (const float*)d_in[15];
    const float* g1 = (const float*)d_in[16];
    const float* b1n = (const float*)d_in[17];
    float* out = (float*)d_out;

    const size_t MD = (size_t)M_ * D_;
    float* ws   = (float*)d_ws;
    float* qbuf = ws;            // [n,h,l,dk]
    float* kbuf = ws + MD;       // [n,h,l,dk]; later ff2 output
    float* vbuf = ws + 2 * MD;   // [n,h,l,dk]
    float* cbuf = ws + 3 * MD;   // ctx [n,l,d]
    float* fbuf = ws + 4 * MD;   // ff1 activations [M, FF]
    float* hbuf = out;           // h parked in d_out until final LN

    dim3 blk(256);
    dim3 gD(D_ / 128, M_ / 128);    // (8, 64)
    dim3 gF(FF_ / 128, M_ / 128);   // (32, 64)

    gemm_mfma<0><<<gD, blk, 0, stream>>>(x, WQ, bQ, nullptr, qbuf, M_, D_, D_);
    gemm_mfma<0><<<gD, blk, 0, stream>>>(x, WK, bK, nullptr, kbuf, M_, D_, D_);
    gemm_mfma<0><<<gD, blk, 0, stream>>>(x, WV, bV, nullptr, vbuf, M_, D_, D_);
    attn_k<<<dim3(L_ / 16, NB_ * H_), blk, 0, stream>>>(qbuf, kbuf, vbuf, mask, cbuf);
    gemm_mfma<1><<<gD, blk, 0, stream>>>(cbuf, WO, bO, x, qbuf, M_, D_, D_);     // mha + x
    ln_k<<<dim3(M_), blk, 0, stream>>>(qbuf, g0, b0, hbuf);                       // h
    gemm_mfma<2><<<gF, blk, 0, stream>>>(hbuf, W1, b1, nullptr, fbuf, M_, FF_, D_);
    gemm_mfma<1><<<gD, blk, 0, stream>>>(fbuf, W2, b2, hbuf, kbuf, M_, D_, FF_); // ff + h
    ln_k<<<dim3(M_), blk, 0, stream>>>(kbuf, g1, b1n, out);
}

// Round 6
// 1108.778 us; speedup vs baseline: 3.0686x; 1.3241x over previous
//
#include <hip/hip_runtime.h>
#include <math.h>

#define D_   1024
#define H_   16
#define DK_  64
#define L_   512
#define NB_  16
#define FF_  4096
#define M_   (NB_*L_)   // 8192 tokens
#define EPS_ 1e-5f

typedef __attribute__((ext_vector_type(8))) __bf16 bf16x8;
typedef __attribute__((ext_vector_type(4))) float f32x4;
typedef __attribute__((ext_vector_type(4))) unsigned short us4;
typedef __attribute__((ext_vector_type(8))) unsigned short us8;
typedef __attribute__((ext_vector_type(4))) unsigned int u32x4;

__device__ __forceinline__ float gelu_exact(float x){
    return 0.5f * x * (1.f + erff(x * 0.7071067811865476f));
}

// split fp32 -> bf16 hi (truncate) + bf16 lo (truncated remainder), packed:
// low 16 bits = hi part, high 16 bits = lo part. ~2^-16 rel err on product.
__device__ __forceinline__ unsigned split1(float a){
    unsigned ab = __builtin_bit_cast(unsigned, a);
    unsigned short h = (unsigned short)(ab >> 16);
    float hif = __builtin_bit_cast(float, ab & 0xffff0000u);
    float rem = a - hif;
    unsigned short lo = (unsigned short)(__builtin_bit_cast(unsigned, rem) >> 16);
    return (unsigned)h | ((unsigned)lo << 16);
}

__device__ __forceinline__ void split4v(float4 x, us4& h, us4& lo){
    unsigned p0 = split1(x.x), p1 = split1(x.y), p2 = split1(x.z), p3 = split1(x.w);
    h.x = (unsigned short)p0; lo.x = (unsigned short)(p0 >> 16);
    h.y = (unsigned short)p1; lo.y = (unsigned short)(p1 >> 16);
    h.z = (unsigned short)p2; lo.z = (unsigned short)(p2 >> 16);
    h.w = (unsigned short)p3; lo.w = (unsigned short)(p3 >> 16);
}

__device__ __forceinline__ void split8v(float4 x, float4 y, bf16x8& h, bf16x8& lo){
    us8 hu, lu; unsigned p;
    p = split1(x.x); hu[0]=(unsigned short)p; lu[0]=(unsigned short)(p>>16);
    p = split1(x.y); hu[1]=(unsigned short)p; lu[1]=(unsigned short)(p>>16);
    p = split1(x.z); hu[2]=(unsigned short)p; lu[2]=(unsigned short)(p>>16);
    p = split1(x.w); hu[3]=(unsigned short)p; lu[3]=(unsigned short)(p>>16);
    p = split1(y.x); hu[4]=(unsigned short)p; lu[4]=(unsigned short)(p>>16);
    p = split1(y.y); hu[5]=(unsigned short)p; lu[5]=(unsigned short)(p>>16);
    p = split1(y.z); hu[6]=(unsigned short)p; lu[6]=(unsigned short)(p>>16);
    p = split1(y.w); hu[7]=(unsigned short)p; lu[7]=(unsigned short)(p>>16);
    h = __builtin_bit_cast(bf16x8, hu);
    lo = __builtin_bit_cast(bf16x8, lu);
}

// ---------------------------------------------------------------------------
// Split-bf16 MFMA GEMM: C = A[M,K] @ B[K,N] + bias, fused epilogue.
// EPI 0: scatter [n,h,l,dk]  EPI 1: +res  EPI 2: GELU  EPI 3: scatter V^T [n,h,dk,l]
// ---------------------------------------------------------------------------
template<int EPI>
__global__ __launch_bounds__(256, 2)
void gemm_mfma(const float* __restrict__ A, const float* __restrict__ B,
               const float* __restrict__ bias, const float* __restrict__ res,
               float* __restrict__ C, int M, int N, int K)
{
    __shared__ __align__(16) unsigned short Ah[4096];
    __shared__ __align__(16) unsigned short Al[4096];
    __shared__ __align__(16) unsigned short Bh[4096];
    __shared__ __align__(16) unsigned short Bl[4096];

    const int t = threadIdx.x;
    const int bm = blockIdx.y * 128, bn = blockIdx.x * 128;
    const int l = t & 63, w = t >> 6, wr = w >> 1, wc = w & 1;

    size_t gA[4]; int lA[4];
#pragma unroll
    for (int i = 0; i < 4; ++i) {
        int f = t + 256 * i;
        int r = f >> 3, k0 = (f & 7) * 4;
        gA[i] = (size_t)(bm + r) * K + k0;
        lA[i] = ((r >> 4) << 9) + (((k0 >> 3) << 4) + (r & 15)) * 8 + (k0 & 7);
    }
    const int c = t & 127, kq = t >> 7;
    const size_t gB = (size_t)(kq * 16) * N + bn + c;
    const int lB = ((c >> 4) << 9) + (kq * 2 * 16 + (c & 15)) * 8;

    f32x4 acc[4][4] = {};

    float4 aA[4];
    float  bB[16];
#pragma unroll
    for (int i = 0; i < 4; ++i) aA[i] = *(const float4*)&A[gA[i]];
#pragma unroll
    for (int i = 0; i < 16; ++i) bB[i] = B[gB + (size_t)i * N];

    const int nk = K >> 5;
    for (int ks = 0; ks < nk; ++ks) {
        __syncthreads();
#pragma unroll
        for (int i = 0; i < 4; ++i) {
            us4 h, lo;
            split4v(aA[i], h, lo);
            *(us4*)&Ah[lA[i]] = h;
            *(us4*)&Al[lA[i]] = lo;
        }
        {
            us8 h0, l0, h1, l1;
#pragma unroll
            for (int i = 0; i < 8; ++i) {
                unsigned p = split1(bB[i]);
                h0[i] = (unsigned short)p; l0[i] = (unsigned short)(p >> 16);
            }
#pragma unroll
            for (int i = 0; i < 8; ++i) {
                unsigned p = split1(bB[8 + i]);
                h1[i] = (unsigned short)p; l1[i] = (unsigned short)(p >> 16);
            }
            *(us8*)&Bh[lB] = h0;       *(us8*)&Bl[lB] = l0;
            *(us8*)&Bh[lB + 128] = h1; *(us8*)&Bl[lB + 128] = l1;
        }
        __syncthreads();
        if (ks + 1 < nk) {
            const int ko = (ks + 1) * 32;
#pragma unroll
            for (int i = 0; i < 4; ++i) aA[i] = *(const float4*)&A[gA[i] + ko];
#pragma unroll
            for (int i = 0; i < 16; ++i) bB[i] = B[gB + (size_t)(ko + i) * N];
        }
        bf16x8 ah[4], al4[4];
#pragma unroll
        for (int m = 0; m < 4; ++m) {
            const int idx = (wr * 4 + m) * 512 + l * 8;
            ah[m]  = *(const bf16x8*)&Ah[idx];
            al4[m] = *(const bf16x8*)&Al[idx];
        }
#pragma unroll
        for (int n = 0; n < 4; ++n) {
            const int idx = (wc * 4 + n) * 512 + l * 8;
            bf16x8 bh = *(const bf16x8*)&Bh[idx];
            bf16x8 bl = *(const bf16x8*)&Bl[idx];
#pragma unroll
            for (int m = 0; m < 4; ++m) {
                acc[m][n] = __builtin_amdgcn_mfma_f32_16x16x32_bf16(ah[m],  bh, acc[m][n], 0, 0, 0);
                acc[m][n] = __builtin_amdgcn_mfma_f32_16x16x32_bf16(ah[m],  bl, acc[m][n], 0, 0, 0);
                acc[m][n] = __builtin_amdgcn_mfma_f32_16x16x32_bf16(al4[m], bh, acc[m][n], 0, 0, 0);
            }
        }
    }

#pragma unroll
    for (int n = 0; n < 4; ++n) {
        const int col = bn + wc * 64 + n * 16 + (l & 15);
        const float bv = bias[col];
#pragma unroll
        for (int m = 0; m < 4; ++m) {
            const int rowb = bm + wr * 64 + m * 16 + ((l >> 4) << 2);
#pragma unroll
            for (int j = 0; j < 4; ++j) {
                const int row = rowb + j;
                float v = acc[m][n][j] + bv;
                if (EPI == 0) {
                    const int nb = row >> 9, ll = row & (L_ - 1);
                    const int hh = col >> 6, d = col & (DK_ - 1);
                    C[(((size_t)nb * H_ + hh) * L_ + ll) * DK_ + d] = v;
                } else if (EPI == 1) {
                    v += res[(size_t)row * N + col];
                    C[(size_t)row * N + col] = v;
                } else if (EPI == 2) {
                    C[(size_t)row * N + col] = gelu_exact(v);
                } else {                         // EPI 3: V^T scatter [n,h,dk,l]
                    const int nb = row >> 9, ll = row & (L_ - 1);
                    const int hh = col >> 6, d = col & (DK_ - 1);
                    C[(((size_t)nb * H_ + hh) * DK_ + d) * L_ + ll] = v;
                }
            }
        }
    }
}

// ---------------------------------------------------------------------------
// MFMA flash-ish attention, split-bf16 precision.
// Block: 512 thr (8 waves) x one (n,h) x 64 q-rows. Two-pass, S in LDS.
// S[64][512] u32 (packed split-bf16), XOR-granule swizzle: g ^= (row&7).
// K staged from [n,h,l,dk]; V staged from V^T [n,h,dk,l]. KT=64 keys/tile.
// ---------------------------------------------------------------------------
__global__ __launch_bounds__(512, 1)
void attn_mfma(const float* __restrict__ qb, const float* __restrict__ kb,
               const float* __restrict__ vt, const unsigned char* __restrict__ mask,
               float* __restrict__ ctx)
{
    __shared__ unsigned Sp[64 * 512];                   // 128 KiB
    __shared__ __align__(16) unsigned short KVh[4096];  // 8 KiB
    __shared__ __align__(16) unsigned short KVl[4096];  // 8 KiB

    const int t = threadIdx.x;
    const int l = t & 63, w = t >> 6;
    const int qsub = w & 3;            // wave's 16-q-row group
    const int ksub = w >> 2;           // QK^T: key half of tile; PV: dk half
    const int qt = blockIdx.x;         // 0..7
    const int nh = blockIdx.y;         // 0..255
    const int n = nh >> 4, hh = nh & 15;
    const int q0 = qt * 64;

    const float* qbase = qb + (size_t)nh * L_ * DK_;    // [l][dk]
    const float* kbase = kb + (size_t)nh * L_ * DK_;    // [l][dk]
    const float* vbase = vt + (size_t)nh * DK_ * L_;    // [dk][l]

    // ---- Q fragments in registers (A-layout: row=l&15, k=(l>>4)*8+j) ----
    bf16x8 qh[2], ql[2];
#pragma unroll
    for (int ks = 0; ks < 2; ++ks) {
        const size_t qa = (size_t)(q0 + qsub * 16 + (l & 15)) * DK_ + ks * 32 + (l >> 4) * 8;
        float4 a0 = *(const float4*)&qbase[qa];
        float4 a1 = *(const float4*)&qbase[qa + 4];
        split8v(a0, a1, qh[ks], ql[ks]);
    }

    // ---- phase 1: S = QK^T/8, packed split-bf16 into swizzled Sp ----
    float4 pf[2];
#pragma unroll
    for (int i = 0; i < 2; ++i) {
        int f = t + 512 * i, r = f >> 4, k0 = (f & 15) * 4;
        pf[i] = *(const float4*)&kbase[(size_t)r * DK_ + k0];
    }
    for (int kt = 0; kt < 8; ++kt) {
        __syncthreads();
#pragma unroll
        for (int i = 0; i < 2; ++i) {
            int f = t + 512 * i, r = f >> 4, k0 = (f & 15) * 4;
            int off = (((r >> 4) * 2 + (k0 >> 5)) << 9) + ((((k0 & 31) >> 3) << 4) + (r & 15)) * 8 + (k0 & 7);
            us4 h, lo; split4v(pf[i], h, lo);
            *(us4*)&KVh[off] = h; *(us4*)&KVl[off] = lo;
        }
        __syncthreads();
        if (kt < 7) {
#pragma unroll
            for (int i = 0; i < 2; ++i) {
                int f = t + 512 * i, r = f >> 4, k0 = (f & 15) * 4;
                pf[i] = *(const float4*)&kbase[(size_t)((kt + 1) * 64 + r) * DK_ + k0];
            }
        }
        f32x4 acc2[2] = {};
#pragma unroll
        for (int ks = 0; ks < 2; ++ks) {
#pragma unroll
            for (int b = 0; b < 2; ++b) {
                const int off = (((ksub * 2 + b) * 2 + ks) << 9) + l * 8;
                bf16x8 bh = *(const bf16x8*)&KVh[off];
                bf16x8 bl = *(const bf16x8*)&KVl[off];
                acc2[b] = __builtin_amdgcn_mfma_f32_16x16x32_bf16(qh[ks], bh, acc2[b], 0, 0, 0);
                acc2[b] = __builtin_amdgcn_mfma_f32_16x16x32_bf16(qh[ks], bl, acc2[b], 0, 0, 0);
                acc2[b] = __builtin_amdgcn_mfma_f32_16x16x32_bf16(ql[ks], bh, acc2[b], 0, 0, 0);
            }
        }
#pragma unroll
        for (int b = 0; b < 2; ++b) {
            const int col = kt * 64 + (ksub * 2 + b) * 16 + (l & 15);
#pragma unroll
            for (int j = 0; j < 4; ++j) {
                const int row = qsub * 16 + (l >> 4) * 4 + j;
                const int word = row * 512 + ((((col >> 2) ^ (row & 7)) << 2) | (col & 3));
                Sp[word] = split1(acc2[b][j] * 0.125f);
            }
        }
    }
    __syncthreads();

    // ---- softmax (no max-shift: scores bounded; masked -> P=0) ----
    {
        const int row = t >> 3, seg = t & 7;
        const unsigned* mrow = (const unsigned*)(mask + ((size_t)n * L_ + q0 + row) * L_ + seg * 64);
        unsigned mb[16];
#pragma unroll
        for (int j2 = 0; j2 < 16; ++j2) mb[j2] = mrow[j2];
        float sum = 0.f;
#pragma unroll
        for (int i = 0; i < 64; ++i) {
            const int col = seg * 64 + i;
            const int word = row * 512 + ((((col >> 2) ^ (row & 7)) << 2) | (i & 3));
            unsigned u = Sp[word];
            float val = __builtin_bit_cast(float, (u & 0xffffu) << 16)
                      + __builtin_bit_cast(float, u & 0xffff0000u);
            if (!((mb[i >> 2] >> ((i & 3) * 8)) & 0xffu)) sum += __expf(val);
        }
        sum += __shfl_xor(sum, 1); sum += __shfl_xor(sum, 2); sum += __shfl_xor(sum, 4);
        const float inv = sum > 0.f ? 1.f / sum : 0.f;
#pragma unroll
        for (int i = 0; i < 64; ++i) {
            const int col = seg * 64 + i;
            const int word = row * 512 + ((((col >> 2) ^ (row & 7)) << 2) | (i & 3));
            unsigned u = Sp[word];
            float val = __builtin_bit_cast(float, (u & 0xffffu) << 16)
                      + __builtin_bit_cast(float, u & 0xffff0000u);
            float p = ((mb[i >> 2] >> ((i & 3) * 8)) & 0xffu) ? 0.f : __expf(val) * inv;
            Sp[word] = split1(p);
        }
    }

    // ---- phase 2: ctx = P V  (V^T staged like K; wave: qsub x 32-dk half) ----
    f32x4 oacc[2] = {};
#pragma unroll
    for (int i = 0; i < 2; ++i) {
        int f = t + 512 * i, d = f >> 4, key0 = (f & 15) * 4;
        pf[i] = *(const float4*)&vbase[(size_t)d * L_ + key0];
    }
    for (int kt = 0; kt < 8; ++kt) {
        __syncthreads();
#pragma unroll
        for (int i = 0; i < 2; ++i) {
            int f = t + 512 * i, d = f >> 4, key0 = (f & 15) * 4;
            int off = (((d >> 4) * 2 + (key0 >> 5)) << 9) + ((((key0 & 31) >> 3) << 4) + (d & 15)) * 8 + (key0 & 7);
            us4 h, lo; split4v(pf[i], h, lo);
            *(us4*)&KVh[off] = h; *(us4*)&KVl[off] = lo;
        }
        __syncthreads();
        if (kt < 7) {
#pragma unroll
            for (int i = 0; i < 2; ++i) {
                int f = t + 512 * i, d = f >> 4, key0 = (f & 15) * 4;
                pf[i] = *(const float4*)&vbase[(size_t)d * L_ + (kt + 1) * 64 + key0];
            }
        }
#pragma unroll
        for (int ks = 0; ks < 2; ++ks) {
            const int rowpv = qsub * 16 + (l & 15);
            const int sw = rowpv & 7;
            const int g0 = kt * 16 + ks * 8 + (l >> 4) * 2;
            u32x4 Ua = *(const u32x4*)&Sp[rowpv * 512 + ((g0 ^ sw) << 2)];
            u32x4 Ub = *(const u32x4*)&Sp[rowpv * 512 + (((g0 + 1) ^ sw) << 2)];
            us8 hu, lu;
            hu[0]=(unsigned short)Ua[0]; lu[0]=(unsigned short)(Ua[0]>>16);
            hu[1]=(unsigned short)Ua[1]; lu[1]=(unsigned short)(Ua[1]>>16);
            hu[2]=(unsigned short)Ua[2]; lu[2]=(unsigned short)(Ua[2]>>16);
            hu[3]=(unsigned short)Ua[3]; lu[3]=(unsigned short)(Ua[3]>>16);
            hu[4]=(unsigned short)Ub[0]; lu[4]=(unsigned short)(Ub[0]>>16);
            hu[5]=(unsigned short)Ub[1]; lu[5]=(unsigned short)(Ub[1]>>16);
            hu[6]=(unsigned short)Ub[2]; lu[6]=(unsigned short)(Ub[2]>>16);
            hu[7]=(unsigned short)Ub[3]; lu[7]=(unsigned short)(Ub[3]>>16);
            bf16x8 ph = __builtin_bit_cast(bf16x8, hu);
            bf16x8 pl = __builtin_bit_cast(bf16x8, lu);
#pragma unroll
            for (int b = 0; b < 2; ++b) {
                const int off = (((ksub * 2 + b) * 2 + ks) << 9) + l * 8;
                bf16x8 vh = *(const bf16x8*)&KVh[off];
                bf16x8 vl = *(const bf16x8*)&KVl[off];
                oacc[b] = __builtin_amdgcn_mfma_f32_16x16x32_bf16(ph, vh, oacc[b], 0, 0, 0);
                oacc[b] = __builtin_amdgcn_mfma_f32_16x16x32_bf16(ph, vl, oacc[b], 0, 0, 0);
                oacc[b] = __builtin_amdgcn_mfma_f32_16x16x32_bf16(pl, vh, oacc[b], 0, 0, 0);
            }
        }
    }
#pragma unroll
    for (int b = 0; b < 2; ++b) {
        const int col = ksub * 32 + b * 16 + (l & 15);
#pragma unroll
        for (int j = 0; j < 4; ++j) {
            const int rowl = q0 + qsub * 16 + (l >> 4) * 4 + j;
            ctx[((size_t)n * L_ + rowl) * D_ + hh * 64 + col] = oacc[b][j];
        }
    }
}

// ---------------------------------------------------------------------------
// Row LayerNorm
// ---------------------------------------------------------------------------
__global__ __launch_bounds__(256)
void ln_k(const float* __restrict__ in, const float* __restrict__ g,
          const float* __restrict__ b, float* __restrict__ out)
{
    const int row = blockIdx.x, tid = threadIdx.x;
    const float* p = in + (size_t)row * D_;
    float4 v = *(const float4*)&p[tid * 4];
    float s = v.x + v.y + v.z + v.w;
#pragma unroll
    for (int off = 32; off > 0; off >>= 1) s += __shfl_down(s, off);
    __shared__ float wsum[4];
    const int wid = tid >> 6, lane = tid & 63;
    if (lane == 0) wsum[wid] = s;
    __syncthreads();
    const float mu = (wsum[0] + wsum[1] + wsum[2] + wsum[3]) * (1.f / D_);
    const float dx = v.x - mu, dy = v.y - mu, dz = v.z - mu, dw = v.w - mu;
    float q = dx * dx + dy * dy + dz * dz + dw * dw;
#pragma unroll
    for (int off = 32; off > 0; off >>= 1) q += __shfl_down(q, off);
    __syncthreads();
    if (lane == 0) wsum[wid] = q;
    __syncthreads();
    const float var = (wsum[0] + wsum[1] + wsum[2] + wsum[3]) * (1.f / D_);
    const float rs = rsqrtf(var + EPS_);
    const float4 gg = *(const float4*)&g[tid * 4];
    const float4 bb = *(const float4*)&b[tid * 4];
    float4 o;
    o.x = dx * rs * gg.x + bb.x;
    o.y = dy * rs * gg.y + bb.y;
    o.z = dz * rs * gg.z + bb.z;
    o.w = dw * rs * gg.w + bb.w;
    *(float4*)&out[(size_t)row * D_ + tid * 4] = o;
}

// ---------------------------------------------------------------------------
extern "C" void kernel_launch(void* const* d_in, const int* in_sizes, int n_in,
                              void* d_out, int out_size, void* d_ws, size_t ws_size,
                              hipStream_t stream)
{
    const float* x  = (const float*)d_in[0];
    const unsigned char* mask = (const unsigned char*)d_in[1];
    const float* WQ = (const float*)d_in[2];
    const float* bQ = (const float*)d_in[3];
    const float* WK = (const float*)d_in[4];
    const float* bK = (const float*)d_in[5];
    const float* WV = (const float*)d_in[6];
    const float* bV = (const float*)d_in[7];
    const float* WO = (const float*)d_in[8];
    const float* bO = (const float*)d_in[9];
    const float* g0 = (const float*)d_in[10];
    const float* b0 = (const float*)d_in[11];
    const float* W1 = (const float*)d_in[12];
    const float* b1 = (const float*)d_in[13];
    const float* W2 = (const float*)d_in[14];
    const float* b2 = (const float*)d_in[15];
    const float* g1 = (const float*)d_in[16];
    const float* b1n = (const float*)d_in[17];
    float* out = (float*)d_out;

    const size_t MD = (size_t)M_ * D_;
    float* ws   = (float*)d_ws;
    float* qbuf = ws;            // [n,h,l,dk]
    float* kbuf = ws + MD;       // [n,h,l,dk]; later ff2 output
    float* vbuf = ws + 2 * MD;   // V^T [n,h,dk,l]
    float* cbuf = ws + 3 * MD;   // ctx [n,l,d]
    float* fbuf = ws + 4 * MD;   // ff1 activations [M, FF]
    float* hbuf = out;           // h parked in d_out until final LN

    dim3 blk(256);
    dim3 gD(D_ / 128, M_ / 128);    // (8, 64)
    dim3 gF(FF_ / 128, M_ / 128);   // (32, 64)

    gemm_mfma<0><<<gD, blk, 0, stream>>>(x, WQ, bQ, nullptr, qbuf, M_, D_, D_);
    gemm_mfma<0><<<gD, blk, 0, stream>>>(x, WK, bK, nullptr, kbuf, M_, D_, D_);
    gemm_mfma<3><<<gD, blk, 0, stream>>>(x, WV, bV, nullptr, vbuf, M_, D_, D_);   // V^T
    attn_mfma<<<dim3(L_ / 64, NB_ * H_), dim3(512), 0, stream>>>(qbuf, kbuf, vbuf, mask, cbuf);
    gemm_mfma<1><<<gD, blk, 0, stream>>>(cbuf, WO, bO, x, qbuf, M_, D_, D_);     // mha + x
    ln_k<<<dim3(M_), blk, 0, stream>>>(qbuf, g0, b0, hbuf);                       // h
    gemm_mfma<2><<<gF, blk, 0, stream>>>(hbuf, W1, b1, nullptr, fbuf, M_, FF_, D_);
    gemm_mfma<1><<<gD, blk, 0, stream>>>(fbuf, W2, b2, hbuf, kbuf, M_, D_, FF_); // ff + h
    ln_k<<<dim3(M_), blk, 0, stream>>>(kbuf, g1, b1n, out);
}